// Round 1
// 649.974 us; speedup vs baseline: 1.1715x; 1.1715x over previous
//
#include <hip/hip_runtime.h>
#include <cstdint>
#include <cstddef>

#define IN_F   512
#define OUT_F  100000
#define BATCH_N 1024
#define BM 128
#define BN 128
#define BK 32

#define SCALE_F 20.0f
#define COS_M 0.8775825618903728f   // cos(0.5)
#define SIN_M 0.4794255386042030f   // sin(0.5)

typedef short s16x8 __attribute__((ext_vector_type(8)));
typedef float f32x4 __attribute__((ext_vector_type(4)));

__device__ __forceinline__ unsigned int f2bf_bits(float x) {
  union { float f; unsigned int u; } v; v.f = x;
  return (v.u + 0x7fffu + ((v.u >> 16) & 1u)) >> 16;  // RNE f32->bf16
}

// One wave per row: L2-normalize a 512-float row, emit bf16.
// Reads are fully coalesced (lane, lane+64 -> two 1KB contiguous bursts) and
// nontemporal (weights f32 are read exactly once; don't pollute LLC -- the
// bf16 output IS re-read by the GEMM and stays cached).
__global__ __launch_bounds__(256) void normalize_rows_bf16(
    const float* __restrict__ in, unsigned short* __restrict__ out, int rows) {
  const int gw   = (int)((blockIdx.x * 256u + threadIdx.x) >> 6);
  const int lane = threadIdx.x & 63;
  if (gw >= rows) return;
  const f32x4* rp = (const f32x4*)(in + (size_t)gw * IN_F);
  f32x4 a = __builtin_nontemporal_load(rp + lane);
  f32x4 b = __builtin_nontemporal_load(rp + lane + 64);
  float s = a.x*a.x + a.y*a.y + a.z*a.z + a.w*a.w
          + b.x*b.x + b.y*b.y + b.z*b.z + b.w*b.w;
  #pragma unroll
  for (int off = 32; off > 0; off >>= 1) s += __shfl_xor(s, off, 64);
  const float sc = 1.0f / fmaxf(sqrtf(s), 1e-12f);
  uint2 q0, q1;
  q0.x = f2bf_bits(a.x * sc) | (f2bf_bits(a.y * sc) << 16);
  q0.y = f2bf_bits(a.z * sc) | (f2bf_bits(a.w * sc) << 16);
  q1.x = f2bf_bits(b.x * sc) | (f2bf_bits(b.y * sc) << 16);
  q1.y = f2bf_bits(b.z * sc) | (f2bf_bits(b.w * sc) << 16);
  uint2* op = (uint2*)(out + (size_t)gw * IN_F);
  op[lane]      = q0;   // elements [4*lane, 4*lane+4)
  op[lane + 64] = q1;   // elements [256+4*lane, ...)
}

// 128x128 tile bf16 MFMA GEMM, C[m][n] = A[m,:].B[n,:], fused ArcFace epilogue.
// A: [1024,512] bf16 (normalized features), B: [100000,512] bf16 (normalized W).
__global__ __launch_bounds__(256) void arcface_gemm(
    const unsigned short* __restrict__ A,
    const unsigned short* __restrict__ B,
    const int* __restrict__ targets,
    float* __restrict__ out) {
  __shared__ unsigned short As[BM * BK];
  __shared__ unsigned short Bs[BN * BK];
  __shared__ int s_tgt[BM];

  const int tid  = threadIdx.x;
  const int lane = tid & 63;
  const int wid  = tid >> 6;          // 4 waves
  const int wm   = wid >> 1;          // 2x2 wave grid over 128x128
  const int wn   = wid & 1;

  // --- XCD-aware bijective swizzle (T1) ---
  // Default: linear id L -> XCD L%8, so the 8 M-blocks sharing one B-panel
  // land on 8 different (non-coherent) L2s. Remap so each XCD owns a
  // contiguous chunk of N-panels with ALL their M-blocks.
  // nwg = 8*782 = 6256, divisible by 8 -> simple form is bijective.
  const int L    = (int)(blockIdx.x + gridDim.x * blockIdx.y);
  const int cpx  = (int)(gridDim.x * gridDim.y) >> 3;   // 782
  const int newL = (L & 7) * cpx + (L >> 3);
  const int m0   = (newL & 7) * BM;
  const int n0   = (newL >> 3) * BN;

  if (tid < BM) s_tgt[tid] = targets[m0 + tid];

  f32x4 acc[4][4];
  const f32x4 zero = {0.f, 0.f, 0.f, 0.f};
  #pragma unroll
  for (int i = 0; i < 4; ++i)
    #pragma unroll
    for (int j = 0; j < 4; ++j) acc[i][j] = zero;

  const int lrow = lane >> 2;          // 0..15 : row within a 16-row staging chunk
  const int lcol = (lane & 3) * 8;     // 0,8,16,24 : bf16 col offset
  const int ra0  = wid * 16;           // this wave's first chunk

  const int lc = lane & 15;            // MFMA fragment col / row-in-16
  const int lq = lane >> 4;            // quad
  const int kq = lq * 8;               // k offset within BK for A/B fragments

  for (int kt = 0; kt < IN_F / BK; ++kt) {
    const int k0 = kt * BK;
    if (kt) __syncthreads();

    // ---- stage A (two 16-row chunks per wave), direct global->LDS 16B ----
    {
      const unsigned short* g0 = A + (size_t)(m0 + ra0 + lrow) * IN_F + k0 + lcol;
      __builtin_amdgcn_global_load_lds(
          (const __attribute__((address_space(1))) void*)g0,
          (__attribute__((address_space(3))) void*)&As[ra0 * BK], 16, 0, 0);
      const unsigned short* g1 = A + (size_t)(m0 + ra0 + 64 + lrow) * IN_F + k0 + lcol;
      __builtin_amdgcn_global_load_lds(
          (const __attribute__((address_space(1))) void*)g1,
          (__attribute__((address_space(3))) void*)&As[(ra0 + 64) * BK], 16, 0, 0);
    }
    // ---- stage B (clamp row index for the 100000 % 128 tail tile) ----
    {
      int nr0 = n0 + ra0 + lrow;       if (nr0 >= OUT_F) nr0 = OUT_F - 1;
      const unsigned short* g0 = B + (size_t)nr0 * IN_F + k0 + lcol;
      __builtin_amdgcn_global_load_lds(
          (const __attribute__((address_space(1))) void*)g0,
          (__attribute__((address_space(3))) void*)&Bs[ra0 * BK], 16, 0, 0);
      int nr1 = n0 + ra0 + 64 + lrow;  if (nr1 >= OUT_F) nr1 = OUT_F - 1;
      const unsigned short* g1 = B + (size_t)nr1 * IN_F + k0 + lcol;
      __builtin_amdgcn_global_load_lds(
          (const __attribute__((address_space(1))) void*)g1,
          (__attribute__((address_space(3))) void*)&Bs[(ra0 + 64) * BK], 16, 0, 0);
    }
    __builtin_amdgcn_s_waitcnt(0x0f70);  // vmcnt(0)
    __syncthreads();

    // ---- fragments + 16 MFMA ----
    s16x8 afr[4], bfr[4];
    #pragma unroll
    for (int i = 0; i < 4; ++i)
      afr[i] = *(const s16x8*)&As[(wm * 64 + i * 16 + lc) * BK + kq];
    #pragma unroll
    for (int j = 0; j < 4; ++j)
      bfr[j] = *(const s16x8*)&Bs[(wn * 64 + j * 16 + lc) * BK + kq];
    #pragma unroll
    for (int i = 0; i < 4; ++i)
      #pragma unroll
      for (int j = 0; j < 4; ++j)
        acc[i][j] = __builtin_amdgcn_mfma_f32_16x16x32_bf16(afr[i], bfr[j], acc[i][j], 0, 0, 0);
  }

  // ---- epilogue: clamp, margin at target col, scale, store ----
  // Row-contiguous order (j innermost): the 4 stores covering a row's 256B
  // issue back-to-back -> full-line merges in L2. Nontemporal: output is
  // write-once, never re-read -> don't evict B/A from LLC.
  const int cbase = n0 + wn * 64;
  #pragma unroll
  for (int i = 0; i < 4; ++i) {
    #pragma unroll
    for (int r = 0; r < 4; ++r) {
      const int lrw = wm * 64 + i * 16 + lq * 4 + r;  // local row 0..127
      const int tgt = s_tgt[lrw];
      float* orow = out + (size_t)(m0 + lrw) * OUT_F;
      #pragma unroll
      for (int j = 0; j < 4; ++j) {
        const int col = cbase + j * 16 + lc;
        if (col >= OUT_F) continue;
        float x = acc[i][j][r];
        x = fminf(1.0f, fmaxf(-1.0f, x));
        float y = (col == tgt)
                    ? (x * COS_M - sqrtf(fmaxf(1.0f - x * x, 0.0f)) * SIN_M)
                    : x;
        __builtin_nontemporal_store(SCALE_F * y, &orow[col]);
      }
    }
  }
}

extern "C" void kernel_launch(void* const* d_in, const int* in_sizes, int n_in,
                              void* d_out, int out_size, void* d_ws, size_t ws_size,
                              hipStream_t stream) {
  const float* features = (const float*)d_in[0];
  const int*   targets  = (const int*)d_in[1];
  const float* weights  = (const float*)d_in[2];
  float* out = (float*)d_out;

  unsigned short* fbf = (unsigned short*)d_ws;                  // 1024*512 bf16
  unsigned short* wbf = fbf + (size_t)BATCH_N * IN_F;           // 100000*512 bf16

  // normalize features: 1024 rows -> 1024 waves -> 256 blocks
  normalize_rows_bf16<<<(BATCH_N * 64 + 255) / 256, 256, 0, stream>>>(features, fbf, BATCH_N);
  // normalize weights: 100000 rows -> 25000 blocks
  normalize_rows_bf16<<<(OUT_F * 64 + 255) / 256, 256, 0, stream>>>(weights, wbf, OUT_F);

  dim3 grid(BATCH_N / BM, (OUT_F + BN - 1) / BN);
  arcface_gemm<<<grid, 256, 0, stream>>>(fbf, wbf, targets, out);
}